// Round 1
// baseline (399.970 us; speedup 1.0000x reference)
//
#include <hip/hip_runtime.h>
#include <hip/hip_bf16.h>
#include <stdint.h>

// RoPE attention, B=2 S=2048 D=2048 H=16 hd=128.
// Pipeline: conv(f32->bf16) -> QKV GEMMs (bf16 MFMA) -> RoPE -> V-transpose
//           -> flash attention -> output GEMM (f32 out).

typedef __attribute__((ext_vector_type(4))) float f32x4;
typedef __attribute__((ext_vector_type(8))) short bf16x8;

typedef __attribute__((address_space(3))) unsigned int lds_u32;
typedef __attribute__((address_space(1))) const unsigned int gbl_u32;

__device__ __forceinline__ void async16(const void* g, void* l) {
  __builtin_amdgcn_global_load_lds((gbl_u32*)g, (lds_u32*)l, 16, 0, 0);
}

__device__ __forceinline__ float bf_to_f(unsigned short u) {
  union { unsigned int i; float f; } v; v.i = ((unsigned int)u) << 16; return v.f;
}
__device__ __forceinline__ unsigned short f_to_bf(float f) {
  union { float f; unsigned int i; } v; v.f = f;
  unsigned int r = v.i + 0x7FFFu + ((v.i >> 16) & 1u);  // RNE
  return (unsigned short)(r >> 16);
}

#define B_ 2
#define S_ 2048
#define D_ 2048
#define H_ 16
#define HD_ 128

// ---------------- f32 -> bf16 convert (4 elems/thread) ----------------
__global__ __launch_bounds__(256) void conv_kernel(const float* __restrict__ src,
                                                   unsigned short* __restrict__ dst, int n4) {
  int i = blockIdx.x * 256 + threadIdx.x;
  if (i >= n4) return;
  float4 v = ((const float4*)src)[i];
  uint2 o;
  o.x = (unsigned int)f_to_bf(v.x) | ((unsigned int)f_to_bf(v.y) << 16);
  o.y = (unsigned int)f_to_bf(v.z) | ((unsigned int)f_to_bf(v.w) << 16);
  ((uint2*)dst)[i] = o;
}

// ---------------- rope cos/sin table: [S][64] ----------------
__global__ __launch_bounds__(256) void rope_table_kernel(float* __restrict__ cosT,
                                                         float* __restrict__ sinT) {
  int i = blockIdx.x * 256 + threadIdx.x;  // S*64 entries
  int s = i >> 6, j = i & 63;
  float inv = powf(10000.0f, -(float)(2 * j) * (1.0f / 128.0f));
  float ang = (float)s * inv;
  float sv, cv;
  sincosf(ang, &sv, &cv);
  cosT[i] = cv;
  sinT[i] = sv;
}

// ---------------- GEMM: C[M,N] = A[M,K] * Bmat[N,K]^T (bf16 in, bf16 or f32 out) ---------
// m97 structure: 128x128 tile, BK=32, 4 waves (2x2 of 64x64), global_load_lds w=16.
template <int OUT_F32>
__global__ __launch_bounds__(256, 2) void gemm_bt(const unsigned short* __restrict__ A,
                                                  const unsigned short* __restrict__ Bm,
                                                  unsigned short* __restrict__ Cb,
                                                  float* __restrict__ Cf,
                                                  int M, int N, int K) {
  __shared__ unsigned short sA[128 * 32];
  __shared__ unsigned short sB[128 * 32];
  const int tid = threadIdx.x;
  const int l = tid & 63, wv = tid >> 6;
  const int lane15 = l & 15, lhi = l >> 4;
  const int wm = wv >> 1, wn = wv & 1;
  const int bm = blockIdx.x, bn = blockIdx.y;
  const unsigned short* Ag = A + (size_t)bm * 128 * K;
  const unsigned short* Bg = Bm + (size_t)bn * 128 * K;

  f32x4 acc[4][4];
  const f32x4 zero = {0.f, 0.f, 0.f, 0.f};
#pragma unroll
  for (int i = 0; i < 4; i++)
#pragma unroll
    for (int j = 0; j < 4; j++) acc[i][j] = zero;

  for (int k0 = 0; k0 < K; k0 += 32) {
    __syncthreads();  // all waves done reading previous tile
#pragma unroll
    for (int i = 0; i < 2; i++) {
      int c = i * 256 + tid;           // chunk id, 8 bf16 each; 512 chunks per tile
      int row = c >> 2, col = (c & 3) << 3;
      async16(Ag + (size_t)row * K + k0 + col, &sA[c * 8]);
      async16(Bg + (size_t)row * K + k0 + col, &sB[c * 8]);
    }
    __syncthreads();  // staging complete (barrier drains vmcnt)

    bf16x8 af[4], bfr[4];
#pragma unroll
    for (int i = 0; i < 4; i++)
      af[i] = *(const bf16x8*)&sA[(wm * 64 + i * 16 + lane15) * 32 + lhi * 8];
#pragma unroll
    for (int j = 0; j < 4; j++)
      bfr[j] = *(const bf16x8*)&sB[(wn * 64 + j * 16 + lane15) * 32 + lhi * 8];
#pragma unroll
    for (int i = 0; i < 4; i++)
#pragma unroll
      for (int j = 0; j < 4; j++)
        acc[i][j] = __builtin_amdgcn_mfma_f32_16x16x32_bf16(af[i], bfr[j], acc[i][j], 0, 0, 0);
  }

  // epilogue: C/D layout col=lane&15, row=(lane>>4)*4+r  [m89-verified]
#pragma unroll
  for (int i = 0; i < 4; i++) {
    int m = bm * 128 + wm * 64 + i * 16 + lhi * 4;
#pragma unroll
    for (int j = 0; j < 4; j++) {
      int n = bn * 128 + wn * 64 + j * 16 + lane15;
#pragma unroll
      for (int r = 0; r < 4; r++) {
        if (OUT_F32)
          Cf[(size_t)(m + r) * N + n] = acc[i][j][r];
        else
          Cb[(size_t)(m + r) * N + n] = f_to_bf(acc[i][j][r]);
      }
    }
  }
}

// ---------------- RoPE in-place on Q or K (grid.y selects), 8 elems/thread ------------
__global__ __launch_bounds__(256) void rope_kernel(unsigned short* __restrict__ Q,
                                                   unsigned short* __restrict__ Kt,
                                                   const float* __restrict__ cosT,
                                                   const float* __restrict__ sinT) {
  unsigned short* T = blockIdx.y ? Kt : Q;
  int c = blockIdx.x * 256 + threadIdx.x;  // B*S*D/8 chunks
  size_t off = (size_t)c * 8;
  int d8 = (int)(off & (D_ - 1));          // position within D
  int s = (int)((off >> 11) & (S_ - 1));   // sequence position
  int j0 = (d8 & (HD_ - 1)) >> 1;          // pair index within head (multiple of 4)
  uint4 raw = *(const uint4*)(T + off);
  float4 cv = *(const float4*)(cosT + ((size_t)s << 6) + j0);
  float4 sv = *(const float4*)(sinT + ((size_t)s << 6) + j0);
  unsigned int u[4] = {raw.x, raw.y, raw.z, raw.w};
  float cc[4] = {cv.x, cv.y, cv.z, cv.w};
  float ss[4] = {sv.x, sv.y, sv.z, sv.w};
  unsigned int o[4];
#pragma unroll
  for (int p = 0; p < 4; p++) {
    float re = bf_to_f((unsigned short)(u[p] & 0xffffu));
    float im = bf_to_f((unsigned short)(u[p] >> 16));
    float orr = re * cc[p] - im * ss[p];
    float oi = re * ss[p] + im * cc[p];
    o[p] = (unsigned int)f_to_bf(orr) | ((unsigned int)f_to_bf(oi) << 16);
  }
  uint4 ov;
  ov.x = o[0]; ov.y = o[1]; ov.z = o[2]; ov.w = o[3];
  *(uint4*)(T + off) = ov;
}

// ---------------- V transpose: V[b][s][h*128+d] -> Vt[bh][d][s] ----------------
__global__ __launch_bounds__(256) void transpose_v(const unsigned short* __restrict__ V,
                                                   unsigned short* __restrict__ Vt) {
  __shared__ unsigned short t[64][72];  // pad to 144B rows (16B aligned)
  int bh = blockIdx.z, b = bh >> 4, h = bh & 15;
  int s0 = blockIdx.x * 64, d0 = blockIdx.y * 64;
  const unsigned short* Vg = V + ((size_t)(b * S_ + s0)) * D_ + h * HD_ + d0;
  int tid = threadIdx.x;
#pragma unroll
  for (int i = 0; i < 2; i++) {
    int c = i * 256 + tid;               // 512 chunks of 8
    int row = c >> 3, col = (c & 7) << 3;  // row = s, col = d
    *(uint4*)&t[row][col] = *(const uint4*)(Vg + (size_t)row * D_ + col);
  }
  __syncthreads();
  unsigned short* Vtg = Vt + ((size_t)(bh * HD_ + d0)) * S_ + s0;
#pragma unroll
  for (int i = 0; i < 2; i++) {
    int c = i * 256 + tid;
    int d = c >> 3, sc = (c & 7) << 3;   // d row out, 8 s-cols
    unsigned short vals[8];
#pragma unroll
    for (int j = 0; j < 8; j++) vals[j] = t[sc + j][d];
    *(uint4*)(Vtg + (size_t)d * S_ + sc) = *(const uint4*)vals;
  }
}

// ---------------- flash attention ----------------
// grid: x = q-tile (S/64), y = bh (32). 4 waves, each owns 16 q-rows.
// K tile [64][128] and Vt tile [128][64] XOR-swizzled in LDS; P via padded per-wave LDS.
__global__ __launch_bounds__(256, 2) void attn_kernel(const unsigned short* __restrict__ Q,
                                                      const unsigned short* __restrict__ K,
                                                      const unsigned short* __restrict__ Vt,
                                                      unsigned short* __restrict__ ctx) {
  __shared__ unsigned short sK[64 * 128];
  __shared__ unsigned short sV[128 * 64];
  __shared__ unsigned short sP[4][16 * 72];
  const int tid = threadIdx.x, l = tid & 63, w = tid >> 6;
  const int lane15 = l & 15, lhi = l >> 4;
  const int bh = blockIdx.y, b = bh >> 4, h = bh & 15;
  const int q0 = blockIdx.x * 64;
  const unsigned short* Qg = Q + ((size_t)(b * S_ + q0 + w * 16)) * D_ + h * HD_;
  const unsigned short* Kg = K + ((size_t)(b * S_)) * D_ + h * HD_;
  const unsigned short* Vg = Vt + ((size_t)bh * HD_) * S_;

  // Q fragments in registers (A-operand: row = lane&15, k = (lane>>4)*8 contiguous)
  bf16x8 qf[4];
#pragma unroll
  for (int kc = 0; kc < 4; kc++)
    qf[kc] = *(const bf16x8*)(Qg + (size_t)lane15 * D_ + kc * 32 + lhi * 8);

  float mrun[4], lrun[4];
#pragma unroll
  for (int r = 0; r < 4; r++) { mrun[r] = -1e30f; lrun[r] = 0.f; }
  const f32x4 zero = {0.f, 0.f, 0.f, 0.f};
  f32x4 oacc[8];
#pragma unroll
  for (int nf = 0; nf < 8; nf++) oacc[nf] = zero;
  const float scale = 0.08838834764831845f;  // 1/sqrt(128)

  for (int k0 = 0; k0 < S_; k0 += 64) {
    __syncthreads();  // previous tile fully consumed
    // stage K tile (64 rows x 128 cols), swizzle byte ^= ((row&7)<<4)
#pragma unroll
    for (int i = 0; i < 4; i++) {
      int c = i * 256 + tid;                 // 1024 chunks of 16B
      int row = c >> 4, colB = (c & 15) << 4;
      uint4 v = *(const uint4*)(Kg + (size_t)(k0 + row) * D_ + (colB >> 1));
      *(uint4*)((char*)sK + row * 256 + (colB ^ ((row & 7) << 4))) = v;
    }
    // stage Vt tile (128 rows x 64 cols), same swizzle
#pragma unroll
    for (int i = 0; i < 4; i++) {
      int c = i * 256 + tid;
      int row = c >> 3, colB = (c & 7) << 4;
      uint4 v = *(const uint4*)(Vg + (size_t)row * S_ + k0 + (colB >> 1));
      *(uint4*)((char*)sV + row * 128 + (colB ^ ((row & 7) << 4))) = v;
    }
    __syncthreads();

    // S = Q K^T  (16x64 stripe per wave)
    f32x4 sacc[4];
#pragma unroll
    for (int n = 0; n < 4; n++) sacc[n] = zero;
#pragma unroll
    for (int n = 0; n < 4; n++) {
      int row = n * 16 + lane15;
#pragma unroll
      for (int kc = 0; kc < 4; kc++) {
        bf16x8 kf = *(const bf16x8*)((char*)sK + row * 256 +
                                     ((kc * 64 + lhi * 16) ^ ((row & 7) << 4)));
        sacc[n] = __builtin_amdgcn_mfma_f32_16x16x32_bf16(qf[kc], kf, sacc[n], 0, 0, 0);
      }
    }

    // online softmax (rows r: q-local = lhi*4+r; 16 lanes of a group share a row)
    float p[4][4];
#pragma unroll
    for (int r = 0; r < 4; r++) {
      float mx = fmaxf(fmaxf(sacc[0][r], sacc[1][r]), fmaxf(sacc[2][r], sacc[3][r])) * scale;
#pragma unroll
      for (int mk = 1; mk < 16; mk <<= 1) mx = fmaxf(mx, __shfl_xor(mx, mk));
      float mnew = fmaxf(mrun[r], mx);
      float alpha = __expf(mrun[r] - mnew);
      float rs = 0.f;
#pragma unroll
      for (int n = 0; n < 4; n++) {
        float pv = __expf(sacc[n][r] * scale - mnew);
        p[n][r] = pv;
        rs += pv;
      }
#pragma unroll
      for (int mk = 1; mk < 16; mk <<= 1) rs += __shfl_xor(rs, mk);
      lrun[r] = lrun[r] * alpha + rs;
      mrun[r] = mnew;
#pragma unroll
      for (int nf = 0; nf < 8; nf++) oacc[nf][r] *= alpha;
    }

    // P (C-layout) -> per-wave LDS (A-layout source), padded stride 72
#pragma unroll
    for (int r = 0; r < 4; r++)
#pragma unroll
      for (int n = 0; n < 4; n++)
        sP[w][(lhi * 4 + r) * 72 + n * 16 + lane15] = f_to_bf(p[n][r]);
    // wave-local write->read fence (cross-lane hazard; keep reads below)
    asm volatile("s_waitcnt lgkmcnt(0)" ::: "memory");
    __builtin_amdgcn_sched_barrier(0);

    bf16x8 pf[2];
#pragma unroll
    for (int kc = 0; kc < 2; kc++)
      pf[kc] = *(const bf16x8*)&sP[w][lane15 * 72 + kc * 32 + lhi * 8];

    // O += P * V   (B-operand from Vt: row=d, k contiguous)
#pragma unroll
    for (int nf = 0; nf < 8; nf++) {
      int row = nf * 16 + lane15;
#pragma unroll
      for (int kc = 0; kc < 2; kc++) {
        bf16x8 vf = *(const bf16x8*)((char*)sV + row * 128 +
                                     ((kc * 64 + lhi * 16) ^ ((row & 7) << 4)));
        oacc[nf] = __builtin_amdgcn_mfma_f32_16x16x32_bf16(pf[kc], vf, oacc[nf], 0, 0, 0);
      }
    }
  }

  // epilogue: ctx[b][q][h][d]
  unsigned short* Og = ctx + ((size_t)(b * S_ + q0 + w * 16)) * D_ + h * HD_;
#pragma unroll
  for (int r = 0; r < 4; r++) {
    float inv = 1.0f / lrun[r];
    int qrow = lhi * 4 + r;
#pragma unroll
    for (int nf = 0; nf < 8; nf++)
      Og[(size_t)qrow * D_ + nf * 16 + lane15] = f_to_bf(oacc[nf][r] * inv);
  }
}

// ---------------- launcher ----------------
extern "C" void kernel_launch(void* const* d_in, const int* in_sizes, int n_in,
                              void* d_out, int out_size, void* d_ws, size_t ws_size,
                              hipStream_t stream) {
  (void)in_sizes; (void)n_in; (void)out_size; (void)ws_size;
  const float* x = (const float*)d_in[0];
  const float* wq = (const float*)d_in[1];
  const float* wk = (const float*)d_in[2];
  const float* wv = (const float*)d_in[3];
  const float* wo = (const float*)d_in[4];
  float* out = (float*)d_out;

  char* ws = (char*)d_ws;
  const size_t MB = 1024 * 1024;
  unsigned short* xb  = (unsigned short*)(ws + 0 * MB);    // 16 MB; later aliased as ctx
  unsigned short* wqb = (unsigned short*)(ws + 16 * MB);   // 8 MB
  unsigned short* wkb = (unsigned short*)(ws + 24 * MB);   // 8 MB
  unsigned short* wvb = (unsigned short*)(ws + 32 * MB);   // 8 MB
  unsigned short* wob = (unsigned short*)(ws + 40 * MB);   // 8 MB
  unsigned short* Qb  = (unsigned short*)(ws + 48 * MB);   // 16 MB
  unsigned short* Kb  = (unsigned short*)(ws + 64 * MB);   // 16 MB
  unsigned short* Vb  = (unsigned short*)(ws + 80 * MB);   // 16 MB
  float* cosT = (float*)(ws + 96 * MB);                    // 0.5 MB
  float* sinT = (float*)(ws + 96 * MB + 524288);           // 0.5 MB
  // aliases (lifetimes disjoint):
  unsigned short* Vtb  = wqb;  // 16 MB spanning wqb+wkb, used after QKV GEMMs
  unsigned short* ctxb = xb;   // x_bf16 dead after QKV GEMMs

  const int M = B_ * S_;  // 4096

  // 1. converts + rope table
  conv_kernel<<<8192, 256, 0, stream>>>(x, xb, (B_ * S_ * D_) / 4);
  conv_kernel<<<4096, 256, 0, stream>>>(wq, wqb, (D_ * D_) / 4);
  conv_kernel<<<4096, 256, 0, stream>>>(wk, wkb, (D_ * D_) / 4);
  conv_kernel<<<4096, 256, 0, stream>>>(wv, wvb, (D_ * D_) / 4);
  conv_kernel<<<4096, 256, 0, stream>>>(wo, wob, (D_ * D_) / 4);
  rope_table_kernel<<<512, 256, 0, stream>>>(cosT, sinT);

  // 2. QKV projections
  dim3 ggrid(M / 128, D_ / 128);
  gemm_bt<0><<<ggrid, 256, 0, stream>>>(xb, wqb, Qb, nullptr, M, D_, D_);
  gemm_bt<0><<<ggrid, 256, 0, stream>>>(xb, wkb, Kb, nullptr, M, D_, D_);
  gemm_bt<0><<<ggrid, 256, 0, stream>>>(xb, wvb, Vb, nullptr, M, D_, D_);

  // 3. RoPE on Q and K
  rope_kernel<<<dim3((B_ * S_ * D_) / 8 / 256, 2), 256, 0, stream>>>(Qb, Kb, cosT, sinT);

  // 4. V transpose -> Vt[bh][d][s]
  transpose_v<<<dim3(S_ / 64, HD_ / 64, B_ * H_), 256, 0, stream>>>(Vb, Vtb);

  // 5. flash attention
  attn_kernel<<<dim3(S_ / 64, B_ * H_), 256, 0, stream>>>(Qb, Kb, Vtb, ctxb);

  // 6. output projection (f32 out)
  gemm_bt<1><<<ggrid, 256, 0, stream>>>(ctxb, wob, nullptr, out, M, D_, D_);
}